// Round 7
// baseline (332.495 us; speedup 1.0000x reference)
//
#include <hip/hip_runtime.h>
#include <stdint.h>

typedef __attribute__((ext_vector_type(8))) short short8;
typedef __attribute__((ext_vector_type(4))) float f32x4;

#define T_STEPS 256
#define BATCH   128

// LDS-visibility barrier that does NOT drain vmcnt (global prefetch stays in flight)
#define LDS_BARRIER() asm volatile("s_waitcnt lgkmcnt(0)\n\ts_barrier" ::: "memory")

static __device__ inline unsigned short f2bf(float f) {   // RNE fp32->bf16 (W2 hi/lo path)
    unsigned int u = __float_as_uint(f);
    unsigned int r = u + 0x7FFFu + ((u >> 16) & 1u);
    return (unsigned short)(r >> 16);
}
static __device__ inline unsigned pack_hi16(unsigned a, unsigned b) {
    return (a >> 16) | (b & 0xFFFF0000u);
}

// ---- k_prep: blocks 0..255 -> W2 hi/lo split; 256..257 -> W1 3-split rows (scaled 1/thr1);
//      blocks 258..769 -> X B-fragments (normalized, exact 3-way bf16 trunc split)
// W1rows[h][64]: [0..15]=Wh, [16..31]=Wm, [32..47]=Wl, [48..63]=0  (W' = W1 / thr1[h])
// Xf[t][btile][frag3][lane64]: B1=[xh|xh], B2=[xm|xm], B3=[xl|xh]
__global__ __launch_bounds__(256) void k_prep(
    const float* __restrict__ W2, const float* __restrict__ W1,
    const float* __restrict__ b1, const float* __restrict__ thr1,
    const float* __restrict__ imin_p, const float* __restrict__ imax_p,
    const float* __restrict__ batch,
    unsigned short* __restrict__ W2hi, unsigned short* __restrict__ W2lo,
    unsigned short* __restrict__ W1rows, float* __restrict__ b1s,
    unsigned short* __restrict__ Xf)
{
    int blk = blockIdx.x, tid = threadIdx.x;
    if (blk < 256) {
        int gid = blk * 256 + tid;          // 65536 threads, 4 elems each
        f32x4 wv = *(const f32x4*)(W2 + (size_t)gid * 4);
        unsigned short hi[4], lo[4];
#pragma unroll
        for (int e = 0; e < 4; ++e) {
            float wf = wv[e];
            unsigned short h = f2bf(wf);
            float hf = __uint_as_float(((unsigned int)h) << 16);
            hi[e] = h;
            lo[e] = f2bf(wf - hf);
        }
        uint2 ph, pl;
        ph.x = (unsigned)hi[0] | ((unsigned)hi[1] << 16);
        ph.y = (unsigned)hi[2] | ((unsigned)hi[3] << 16);
        pl.x = (unsigned)lo[0] | ((unsigned)lo[1] << 16);
        pl.y = (unsigned)lo[2] | ((unsigned)lo[3] << 16);
        *(uint2*)(W2hi + (size_t)gid * 4) = ph;
        *(uint2*)(W2lo + (size_t)gid * 4) = pl;
    } else if (blk < 258) {
        int h = (blk - 256) * 256 + tid;    // 512 rows
        float wsc = 1.0f / thr1[h];
        unsigned short row[64];
#pragma unroll
        for (int k = 0; k < 16; ++k) {
            float wv = W1[h * 16 + k] * wsc;
            unsigned a = __float_as_uint(wv) & 0xFFFF0000u;
            float r1 = wv - __uint_as_float(a);
            unsigned m = __float_as_uint(r1) & 0xFFFF0000u;
            float r2 = r1 - __uint_as_float(m);
            unsigned l = __float_as_uint(r2) & 0xFFFF0000u;
            row[k]      = (unsigned short)(a >> 16);
            row[16 + k] = (unsigned short)(m >> 16);
            row[32 + k] = (unsigned short)(l >> 16);
            row[48 + k] = 0;
        }
        b1s[h] = b1[h] * wsc;
        uint4* dst = (uint4*)(W1rows + (size_t)h * 64);
#pragma unroll
        for (int i = 0; i < 8; ++i) dst[i] = ((uint4*)row)[i];
    } else {
        int gid   = (blk - 258) * 256 + tid;   // 131072 = 256t * 8btile * 64lane
        int lane  = gid & 63;
        int btile = (gid >> 6) & 7;
        int t     = gid >> 9;
        int q     = lane >> 4, m15 = lane & 15;
        int b     = btile * 16 + m15;
        float imin = imin_p[0];
        float isc  = 1.0f / (imax_p[0] - imin);
        const float* xp = batch + ((size_t)b * T_STEPS + t) * 16 + (q & 1) * 8;
        unsigned uh[8], um[8], ul[8];
#pragma unroll
        for (int j = 0; j < 8; ++j) {
            float xv = (xp[j] - imin) * isc;
            unsigned a = __float_as_uint(xv) & 0xFFFF0000u;
            float r1 = xv - __uint_as_float(a);
            unsigned m = __float_as_uint(r1) & 0xFFFF0000u;
            float r2 = r1 - __uint_as_float(m);
            unsigned l = __float_as_uint(r2) & 0xFFFF0000u;
            uh[j] = a; um[j] = m; ul[j] = l;
        }
        uint4 B1, B2, XL;
        B1.x = pack_hi16(uh[0], uh[1]); B1.y = pack_hi16(uh[2], uh[3]);
        B1.z = pack_hi16(uh[4], uh[5]); B1.w = pack_hi16(uh[6], uh[7]);
        B2.x = pack_hi16(um[0], um[1]); B2.y = pack_hi16(um[2], um[3]);
        B2.z = pack_hi16(um[4], um[5]); B2.w = pack_hi16(um[6], um[7]);
        XL.x = pack_hi16(ul[0], ul[1]); XL.y = pack_hi16(ul[2], ul[3]);
        XL.z = pack_hi16(ul[4], ul[5]); XL.w = pack_hi16(ul[6], ul[7]);
        uint4 B3 = (q < 2) ? XL : B1;   // [xl|xh]
        unsigned short* dst = Xf + (((size_t)t * 8 + btile) * 3) * 512 + lane * 8;
        *(uint4*)(dst +    0) = B1;
        *(uint4*)(dst +  512) = B2;
        *(uint4*)(dst + 1024) = B3;
    }
}

// ---- main: 1024 threads (16 waves); software-pipelined reduce; all LDS conflict-free
__global__ __launch_bounds__(1024, 4) void k_main(
    const unsigned short* __restrict__ Xf,
    const unsigned short* __restrict__ W2hi, const unsigned short* __restrict__ W2lo,
    const unsigned short* __restrict__ W1rows, const float* __restrict__ b1s,
    const float* __restrict__ beta1, const float* __restrict__ b2,
    const float* __restrict__ beta2, const float* __restrict__ thr2,
    unsigned short* __restrict__ spkbits)
{
    __shared__ unsigned short Aw[8192];   // 16 waves x 1KB wave-private spike staging
    __shared__ float Cbuf[2][4096];       // [buf][r 4][wp 16][lane 64] — lane-stride-1
    __shared__ float Sbuf[1024];          // [r 4][g 4][lane 64] stage-2 exchange

    int tid  = threadIdx.x;
    int lane = tid & 63;
    int w    = tid >> 6;                  // 0..15: GEMM1 h-chunk of 32 = GEMM2 K-chunk of 32
    int q    = lane >> 4, m15 = lane & 15;
    int btile = blockIdx.x & 7;
    int slice = blockIdx.x >> 3;
    int rr   = w & 3, gg = w >> 2;

    // W1 A-frags: A1=[Wh|Wm], A2=[Wh|Wl]
    short8 A1[2], A2[2];
#pragma unroll
    for (int c = 0; c < 2; ++c) {
        const unsigned short* rp = W1rows + (size_t)(w * 32 + c * 16 + m15) * 64;
        A1[c] = *(const short8*)(rp + q * 8);
        A2[c] = *(const short8*)(rp + q * 8 + (q >> 1) * 16);
    }
    // W2 B-frags for K-window [w*32, w*32+32)
    int jg = slice * 16 + m15;
    short8 bhi = *(const short8*)(W2hi + (size_t)jg * 512 + w * 32 + q * 8);
    short8 blo = *(const short8*)(W2lo + (size_t)jg * 512 + w * 32 + q * 8);

    // LIF1 params: states (b=m15, h = w*32 + c*16 + q*4 + r)
    f32x4 b14[2], bet1[2];
#pragma unroll
    for (int c = 0; c < 2; ++c) {
        int h0 = w * 32 + c * 16 + q * 4;
        b14[c] = *(const f32x4*)(b1s + h0);
        f32x4 bb = *(const f32x4*)(beta1 + h0);
#pragma unroll
        for (int r = 0; r < 4; ++r) bet1[c][r] = fminf(fmaxf(bb[r], 0.0f), 1.0f);
    }
    float m1[8], spk1f[8];
#pragma unroll
    for (int i = 0; i < 8; ++i) { m1[i] = 0.0f; spk1f[i] = 0.0f; }

    // LIF2: lane item (b = (lane>>4)*4 + rr, j = jg); replicated across 4 waves w/ same rr
    float beta2r = fminf(fmaxf(beta2[jg], 0.0f), 1.0f);
    float thr2r  = thr2[jg];
    float nthr2  = -thr2r;
    float b2r    = b2[jg];
    float m2 = 0.0f, spk2f = 0.0f;

    const unsigned short* xbase = Xf + ((size_t)btile * 3) * 512 + lane * 8;
    uint4 xA[3], xB[3];
#pragma unroll
    for (int f = 0; f < 3; ++f) xA[f] = *(const uint4*)(xbase + f * 512);

    unsigned short* myAw = Aw + w * 512;
    int wr0 = (0 * 2 + (q >> 1)) * 128 + (m15 ^ (q >> 1)) * 8 + (q & 1) * 4;
    int wr1 = (1 * 2 + (q >> 1)) * 128 + (m15 ^ (q >> 1)) * 8 + (q & 1) * 4;
    int rdo = (q * 16 + (m15 ^ (q & 1))) * 8;

    // compute step k (GEMM1->LIF1->GEMM2), scatter partials into Cbuf[k&1]
    auto W = [&](int k, uint4* xcur, uint4* xnx) __attribute__((always_inline)) {
        int tn = (k + 1 < T_STEPS) ? k + 1 : k;
        const unsigned short* xp = xbase + (size_t)tn * 12288;
#pragma unroll
        for (int f = 0; f < 3; ++f) xnx[f] = *(const uint4*)(xp + f * 512);

        union { uint4 u; short8 s; } Bf[3];
#pragma unroll
        for (int f = 0; f < 3; ++f) Bf[f].u = xcur[f];
        f32x4 D[2];
#pragma unroll
        for (int c = 0; c < 2; ++c) {
            D[c] = b14[c];
            D[c] = __builtin_amdgcn_mfma_f32_16x16x32_bf16(A1[c], Bf[0].s, D[c], 0, 0, 0);
            D[c] = __builtin_amdgcn_mfma_f32_16x16x32_bf16(A1[c], Bf[1].s, D[c], 0, 0, 0);
            D[c] = __builtin_amdgcn_mfma_f32_16x16x32_bf16(A2[c], Bf[2].s, D[c], 0, 0, 0);
        }
#pragma unroll
        for (int i = 0; i < 8; ++i) {
            int c = i >> 2, r = i & 3;
            float mv = fmaf(bet1[c][r], m1[i], D[c][r]);
            mv -= spk1f[i];
            bool sp = mv > 1.0f;
            m1[i] = mv;
            spk1f[i] = sp ? 1.0f : 0.0f;
        }
        {
            uint2 pk0, pk1;
            pk0.x = pack_hi16(__float_as_uint(spk1f[0]), __float_as_uint(spk1f[1]));
            pk0.y = pack_hi16(__float_as_uint(spk1f[2]), __float_as_uint(spk1f[3]));
            pk1.x = pack_hi16(__float_as_uint(spk1f[4]), __float_as_uint(spk1f[5]));
            pk1.y = pack_hi16(__float_as_uint(spk1f[6]), __float_as_uint(spk1f[7]));
            *(uint2*)(myAw + wr0) = pk0;
            *(uint2*)(myAw + wr1) = pk1;
        }
        union { uint4 u; short8 s; } af;
        af.u = *(uint4*)(myAw + rdo);
        f32x4 C2 = { 0.f, 0.f, 0.f, 0.f };
        C2 = __builtin_amdgcn_mfma_f32_16x16x32_bf16(af.s, bhi, C2, 0, 0, 0);
        C2 = __builtin_amdgcn_mfma_f32_16x16x32_bf16(af.s, blo, C2, 0, 0, 0);
        float* cb = Cbuf[k & 1];
#pragma unroll
        for (int r = 0; r < 4; ++r)
            cb[r * 1024 + w * 64 + lane] = C2[r];
    };
    // stage 1: wave w sums its wp-group (gg) for row rr — conflict-free stride-64 reads
    auto S1 = [&](int i) __attribute__((always_inline)) {
        const float* cb = Cbuf[i & 1];
        float s0 = cb[rr * 1024 + (gg * 4 + 0) * 64 + lane];
        float s1 = cb[rr * 1024 + (gg * 4 + 1) * 64 + lane];
        float s2 = cb[rr * 1024 + (gg * 4 + 2) * 64 + lane];
        float s3 = cb[rr * 1024 + (gg * 4 + 3) * 64 + lane];
        Sbuf[(rr * 4 + gg) * 64 + lane] = (s0 + s1) + (s2 + s3);
    };
    // stage 2: full sum for row rr + LIF2 + spike-bit store (replicated x4, identical)
    auto S2 = [&](int i) __attribute__((always_inline)) {
        float s0 = Sbuf[(rr * 4 + 0) * 64 + lane];
        float s1 = Sbuf[(rr * 4 + 1) * 64 + lane];
        float s2 = Sbuf[(rr * 4 + 2) * 64 + lane];
        float s3 = Sbuf[(rr * 4 + 3) * 64 + lane];
        float cur2 = b2r + ((s0 + s1) + (s2 + s3));
        m2 = fmaf(beta2r, m2, cur2);
        m2 = fmaf(spk2f, nthr2, m2);
        bool sp2 = m2 > thr2r;
        spk2f = sp2 ? 1.0f : 0.0f;
        unsigned long long mask = __ballot(sp2);
        if (w < 4 && m15 == 0) {
            int p = lane >> 4;   // item b = p*4 + w (rr==w for w<4)
            spkbits[((size_t)i * BATCH + btile * 16 + p * 4 + w) * 32 + slice] =
                (unsigned short)(mask >> (p * 16));
        }
    };

    W(0, xA, xB);
#pragma unroll 1
    for (int i = 0; i < T_STEPS; i += 2) {
        LDS_BARRIER();                 // B1(i): all scatter(i) visible
        W(i + 1, xB, xA);              // independent work hides reduce latency
        S1(i);
        LDS_BARRIER();                 // B2(i): Sbuf visible
        S2(i);
        LDS_BARRIER();                 // B1(i+1)
        if (i + 2 < T_STEPS) W(i + 2, xA, xB);
        S1(i + 1);
        LDS_BARRIER();                 // B2(i+1)
        S2(i + 1);
    }
}

// ---- action bit-GEMM + beta-weighted scan over t (R3..R6-proven) ----
__global__ __launch_bounds__(256) void k_act(
    const unsigned short* __restrict__ spkbits,
    const float* __restrict__ Wa, const float* __restrict__ ba,
    const float* __restrict__ beta_act_p, float* __restrict__ out)
{
    __shared__ f32x4 waT[512];
    __shared__ f32x4 sc[256];
    int tid = threadIdx.x;   // = timestep
    int b   = blockIdx.x;

    for (int j = tid; j < 512; j += 256) {
        f32x4 v = { Wa[j], Wa[512 + j], Wa[1024 + j], Wa[1536 + j] };
        waT[j] = v;
    }
    float bact = fminf(fmaxf(beta_act_p[0], 0.0f), 1.0f);
    f32x4 acc = { ba[0], ba[1], ba[2], ba[3] };
    __syncthreads();

    const unsigned short* sp = spkbits + ((size_t)tid * BATCH + b) * 32;
    unsigned int wbuf[16];
#pragma unroll
    for (int r = 0; r < 4; ++r) {
        uint4 v = *(const uint4*)(sp + r * 8);
        wbuf[r*4+0] = v.x; wbuf[r*4+1] = v.y; wbuf[r*4+2] = v.z; wbuf[r*4+3] = v.w;
    }
    for (int s = 0; s < 32; ++s) {
        unsigned int wd = (wbuf[s >> 1] >> ((s & 1) * 16)) & 0xFFFFu;
#pragma unroll
        for (int i = 0; i < 16; ++i) {
            float sel = ((wd >> i) & 1u) ? 1.0f : 0.0f;
            f32x4 wv = waT[s * 16 + i];
            acc[0] = fmaf(sel, wv[0], acc[0]);
            acc[1] = fmaf(sel, wv[1], acc[1]);
            acc[2] = fmaf(sel, wv[2], acc[2]);
            acc[3] = fmaf(sel, wv[3], acc[3]);
        }
    }
    sc[tid] = acc;
    __syncthreads();
    float bd = bact;
    for (int d = 1; d < 256; d <<= 1) {
        f32x4 cv = sc[tid];
        f32x4 pv = { 0.f, 0.f, 0.f, 0.f };
        if (tid >= d) pv = sc[tid - d];
        __syncthreads();
        cv[0] = fmaf(bd, pv[0], cv[0]);
        cv[1] = fmaf(bd, pv[1], cv[1]);
        cv[2] = fmaf(bd, pv[2], cv[2]);
        cv[3] = fmaf(bd, pv[3], cv[3]);
        sc[tid] = cv;
        __syncthreads();
        bd *= bd;
    }
    f32x4 res = sc[tid];
    *(f32x4*)(out + (size_t)tid * 512 + b * 4) = res;
}

extern "C" void kernel_launch(void* const* d_in, const int* in_sizes, int n_in,
                              void* d_out, int out_size, void* d_ws, size_t ws_size,
                              hipStream_t stream)
{
    const float* batch    = (const float*)d_in[0];
    const float* W1       = (const float*)d_in[1];
    const float* b1       = (const float*)d_in[2];
    const float* beta1    = (const float*)d_in[3];
    const float* thr1     = (const float*)d_in[4];
    const float* W2       = (const float*)d_in[5];
    const float* b2       = (const float*)d_in[6];
    const float* beta2    = (const float*)d_in[7];
    const float* thr2     = (const float*)d_in[8];
    const float* Wa       = (const float*)d_in[9];
    const float* ba       = (const float*)d_in[10];
    const float* beta_act = (const float*)d_in[11];
    const float* inp_min  = (const float*)d_in[12];
    const float* inp_max  = (const float*)d_in[13];
    float* out            = (float*)d_out;

    char* ws = (char*)d_ws;
    unsigned short* W2hi    = (unsigned short*)ws;                          // 512 KiB
    unsigned short* W2lo    = (unsigned short*)(ws + (512u << 10));         // 512 KiB
    unsigned short* W1rows  = (unsigned short*)(ws + (1u << 20));           // 64 KiB
    float*          b1s     = (float*)(ws + (1u << 20) + (64u << 10));      // 2 KiB
    unsigned short* Xf      = (unsigned short*)(ws + (2u << 20));           // 6 MiB
    unsigned short* spkbits = (unsigned short*)(ws + (8u << 20));           // 2 MiB

    hipLaunchKernelGGL(k_prep, dim3(770), dim3(256), 0, stream,
                       W2, W1, b1, thr1, inp_min, inp_max, batch,
                       W2hi, W2lo, W1rows, b1s, Xf);
    hipLaunchKernelGGL(k_main, dim3(256), dim3(1024), 0, stream,
                       Xf, W2hi, W2lo, W1rows, b1s, beta1, b2, beta2, thr2, spkbits);
    hipLaunchKernelGGL(k_act, dim3(128), dim3(256), 0, stream, spkbits, Wa, ba, beta_act, out);
}

// Round 8
// 308.746 us; speedup vs baseline: 1.0769x; 1.0769x over previous
//
#include <hip/hip_runtime.h>
#include <stdint.h>

typedef __attribute__((ext_vector_type(8))) short short8;
typedef __attribute__((ext_vector_type(4))) float f32x4;

#define T_STEPS 256
#define BATCH   128

// LDS-visibility barrier that does NOT drain vmcnt (global prefetch stays in flight)
#define LDS_BARRIER() asm volatile("s_waitcnt lgkmcnt(0)\n\ts_barrier" ::: "memory")

static __device__ inline unsigned short f2bf(float f) {   // RNE fp32->bf16 (W2 hi/lo path)
    unsigned int u = __float_as_uint(f);
    unsigned int r = u + 0x7FFFu + ((u >> 16) & 1u);
    return (unsigned short)(r >> 16);
}
static __device__ inline unsigned pack_hi16(unsigned a, unsigned b) {
    return (a >> 16) | (b & 0xFFFF0000u);
}

// ---- k_prep: blocks 0..255 -> W2 hi/lo split; 256..257 -> W1 3-split rows (scaled 1/thr1);
//      blocks 258..769 -> X B-fragments (normalized, exact 3-way bf16 trunc split)
// W1rows[h][64]: [0..15]=Wh, [16..31]=Wm, [32..47]=Wl, [48..63]=0  (W' = W1 / thr1[h])
// Xf[t][btile][frag3][lane64]: B1=[xh|xh], B2=[xm|xm], B3=[xl|xh]
__global__ __launch_bounds__(256) void k_prep(
    const float* __restrict__ W2, const float* __restrict__ W1,
    const float* __restrict__ b1, const float* __restrict__ thr1,
    const float* __restrict__ imin_p, const float* __restrict__ imax_p,
    const float* __restrict__ batch,
    unsigned short* __restrict__ W2hi, unsigned short* __restrict__ W2lo,
    unsigned short* __restrict__ W1rows, float* __restrict__ b1s,
    unsigned short* __restrict__ Xf)
{
    int blk = blockIdx.x, tid = threadIdx.x;
    if (blk < 256) {
        int gid = blk * 256 + tid;          // 65536 threads, 4 elems each
        f32x4 wv = *(const f32x4*)(W2 + (size_t)gid * 4);
        unsigned short hi[4], lo[4];
#pragma unroll
        for (int e = 0; e < 4; ++e) {
            float wf = wv[e];
            unsigned short h = f2bf(wf);
            float hf = __uint_as_float(((unsigned int)h) << 16);
            hi[e] = h;
            lo[e] = f2bf(wf - hf);
        }
        uint2 ph, pl;
        ph.x = (unsigned)hi[0] | ((unsigned)hi[1] << 16);
        ph.y = (unsigned)hi[2] | ((unsigned)hi[3] << 16);
        pl.x = (unsigned)lo[0] | ((unsigned)lo[1] << 16);
        pl.y = (unsigned)lo[2] | ((unsigned)lo[3] << 16);
        *(uint2*)(W2hi + (size_t)gid * 4) = ph;
        *(uint2*)(W2lo + (size_t)gid * 4) = pl;
    } else if (blk < 258) {
        int h = (blk - 256) * 256 + tid;    // 512 rows
        float wsc = 1.0f / thr1[h];
        unsigned short row[64];
#pragma unroll
        for (int k = 0; k < 16; ++k) {
            float wv = W1[h * 16 + k] * wsc;
            unsigned a = __float_as_uint(wv) & 0xFFFF0000u;
            float r1 = wv - __uint_as_float(a);
            unsigned m = __float_as_uint(r1) & 0xFFFF0000u;
            float r2 = r1 - __uint_as_float(m);
            unsigned l = __float_as_uint(r2) & 0xFFFF0000u;
            row[k]      = (unsigned short)(a >> 16);
            row[16 + k] = (unsigned short)(m >> 16);
            row[32 + k] = (unsigned short)(l >> 16);
            row[48 + k] = 0;
        }
        b1s[h] = b1[h] * wsc;
        uint4* dst = (uint4*)(W1rows + (size_t)h * 64);
#pragma unroll
        for (int i = 0; i < 8; ++i) dst[i] = ((uint4*)row)[i];
    } else {
        int gid   = (blk - 258) * 256 + tid;   // 131072 = 256t * 8btile * 64lane
        int lane  = gid & 63;
        int btile = (gid >> 6) & 7;
        int t     = gid >> 9;
        int q     = lane >> 4, m15 = lane & 15;
        int b     = btile * 16 + m15;
        float imin = imin_p[0];
        float isc  = 1.0f / (imax_p[0] - imin);
        const float* xp = batch + ((size_t)b * T_STEPS + t) * 16 + (q & 1) * 8;
        unsigned uh[8], um[8], ul[8];
#pragma unroll
        for (int j = 0; j < 8; ++j) {
            float xv = (xp[j] - imin) * isc;
            unsigned a = __float_as_uint(xv) & 0xFFFF0000u;
            float r1 = xv - __uint_as_float(a);
            unsigned m = __float_as_uint(r1) & 0xFFFF0000u;
            float r2 = r1 - __uint_as_float(m);
            unsigned l = __float_as_uint(r2) & 0xFFFF0000u;
            uh[j] = a; um[j] = m; ul[j] = l;
        }
        uint4 B1, B2, XL;
        B1.x = pack_hi16(uh[0], uh[1]); B1.y = pack_hi16(uh[2], uh[3]);
        B1.z = pack_hi16(uh[4], uh[5]); B1.w = pack_hi16(uh[6], uh[7]);
        B2.x = pack_hi16(um[0], um[1]); B2.y = pack_hi16(um[2], um[3]);
        B2.z = pack_hi16(um[4], um[5]); B2.w = pack_hi16(um[6], um[7]);
        XL.x = pack_hi16(ul[0], ul[1]); XL.y = pack_hi16(ul[2], ul[3]);
        XL.z = pack_hi16(ul[4], ul[5]); XL.w = pack_hi16(ul[6], ul[7]);
        uint4 B3 = (q < 2) ? XL : B1;   // [xl|xh]
        unsigned short* dst = Xf + (((size_t)t * 8 + btile) * 3) * 512 + lane * 8;
        *(uint4*)(dst +    0) = B1;
        *(uint4*)(dst +  512) = B2;
        *(uint4*)(dst + 1024) = B3;
    }
}

// ---- main: 16 waves; 1 barrier/step; reduce 1 step behind, GEMM1 1 step ahead
__global__ __launch_bounds__(1024, 4) void k_main(
    const unsigned short* __restrict__ Xf,
    const unsigned short* __restrict__ W2hi, const unsigned short* __restrict__ W2lo,
    const unsigned short* __restrict__ W1rows, const float* __restrict__ b1s,
    const float* __restrict__ beta1, const float* __restrict__ b2,
    const float* __restrict__ beta2, const float* __restrict__ thr2,
    unsigned short* __restrict__ spkbits)
{
    __shared__ unsigned short Aw[8192];   // 16 waves x 1KB wave-private spike staging
    __shared__ float Cbuf[2][4096];       // [buf][r 4][wp 16][lane^swz 64]

    int tid  = threadIdx.x;
    int lane = tid & 63;
    int w    = tid >> 6;                  // 0..15: GEMM1 h-chunk of 32 = GEMM2 K-chunk of 32
    int q    = lane >> 4, m15 = lane & 15;
    int btile = blockIdx.x & 7;
    int slice = blockIdx.x >> 3;
    int rr = w & 3, qi = w >> 2;          // reduce wave w owns item b = qi*4 + rr

    // W1 A-frags: A1=[Wh|Wm], A2=[Wh|Wl]
    short8 A1[2], A2[2];
#pragma unroll
    for (int c = 0; c < 2; ++c) {
        const unsigned short* rp = W1rows + (size_t)(w * 32 + c * 16 + m15) * 64;
        A1[c] = *(const short8*)(rp + q * 8);
        A2[c] = *(const short8*)(rp + q * 8 + (q >> 1) * 16);
    }
    // W2 B-frags for K-window [w*32, w*32+32)
    int jg = slice * 16 + m15;
    short8 bhi = *(const short8*)(W2hi + (size_t)jg * 512 + w * 32 + q * 8);
    short8 blo = *(const short8*)(W2lo + (size_t)jg * 512 + w * 32 + q * 8);

    // LIF1 params: states (b=m15, h = w*32 + c*16 + q*4 + r)
    f32x4 b14[2], bet1[2];
#pragma unroll
    for (int c = 0; c < 2; ++c) {
        int h0 = w * 32 + c * 16 + q * 4;
        b14[c] = *(const f32x4*)(b1s + h0);
        f32x4 bb = *(const f32x4*)(beta1 + h0);
#pragma unroll
        for (int r = 0; r < 4; ++r) bet1[c][r] = fminf(fmaxf(bb[r], 0.0f), 1.0f);
    }
    float m1[8], spk1f[8];
#pragma unroll
    for (int i = 0; i < 8; ++i) { m1[i] = 0.0f; spk1f[i] = 0.0f; }

    // LIF2: lane item (b = qi*4 + rr, j = jg); lanes replicate over quads (identical math)
    float beta2r = fminf(fmaxf(beta2[jg], 0.0f), 1.0f);
    float thr2r  = thr2[jg];
    float nthr2  = -thr2r;
    float b2r    = b2[jg];
    float m2 = 0.0f, spk2f = 0.0f;

    // X pointers: A-instance prefetches even t, B odd t; both advance 2 steps/iter
    const unsigned short* xbase = Xf + ((size_t)btile * 3) * 512 + lane * 8;
    const unsigned short* xpA = xbase + 2 * 12288;
    const unsigned short* xpB = xbase + 3 * 12288;
    uint4 xP[3], xQ[3];
#pragma unroll
    for (int f = 0; f < 3; ++f) xP[f] = *(const uint4*)(xbase + f * 512);
#pragma unroll
    for (int f = 0; f < 3; ++f) xQ[f] = *(const uint4*)(xbase + 12288 + f * 512);

    // Aw addresses (ushort units), wave-private
    unsigned short* awp = Aw + w * 512;
    int wr0 = ((q >> 1)) * 128 + (m15 ^ (q >> 1)) * 8 + (q & 1) * 4;
    int wr1 = wr0 + 256;
    int rdo = (q * 16 + (m15 ^ (q & 1))) * 8;
    // scatter / reduce indices (float words)
    int sidx = w * 64 + (lane ^ (qi * 16));                    // + r*1024
    int ridx = rr * 1024 + q * 256 + ((qi ^ q) * 16 + m15);    // + s*64

    unsigned short* spkp = spkbits + ((size_t)btile * 16 + (qi * 4 + rr)) * 32 + slice;

    auto gemm1 = [&](uint4* x, f32x4* D) __attribute__((always_inline)) {
        union { uint4 u; short8 s; } B0, B1, B2;
        B0.u = x[0]; B1.u = x[1]; B2.u = x[2];
#pragma unroll
        for (int c = 0; c < 2; ++c) {
            D[c] = b14[c];
            D[c] = __builtin_amdgcn_mfma_f32_16x16x32_bf16(A1[c], B0.s, D[c], 0, 0, 0);
            D[c] = __builtin_amdgcn_mfma_f32_16x16x32_bf16(A1[c], B1.s, D[c], 0, 0, 0);
            D[c] = __builtin_amdgcn_mfma_f32_16x16x32_bf16(A2[c], B2.s, D[c], 0, 0, 0);
        }
    };
    auto lifpack = [&](f32x4* D) __attribute__((always_inline)) {
#pragma unroll
        for (int i = 0; i < 8; ++i) {
            int c = i >> 2, r = i & 3;
            float mv = fmaf(bet1[c][r], m1[i], D[c][r]);
            mv -= spk1f[i];
            bool sp = mv > 1.0f;
            m1[i] = mv;
            spk1f[i] = sp ? 1.0f : 0.0f;
        }
        uint2 pk0, pk1;
        pk0.x = pack_hi16(__float_as_uint(spk1f[0]), __float_as_uint(spk1f[1]));
        pk0.y = pack_hi16(__float_as_uint(spk1f[2]), __float_as_uint(spk1f[3]));
        pk1.x = pack_hi16(__float_as_uint(spk1f[4]), __float_as_uint(spk1f[5]));
        pk1.y = pack_hi16(__float_as_uint(spk1f[6]), __float_as_uint(spk1f[7]));
        *(uint2*)(awp + wr0) = pk0;
        *(uint2*)(awp + wr1) = pk1;
    };
    auto rtail = [&](float s0, float s1, float s2, float s3) __attribute__((always_inline)) {
        float s = (s0 + s1) + (s2 + s3);
        s += __shfl_xor(s, 16, 64);
        s += __shfl_xor(s, 32, 64);
        m2 = fmaf(beta2r, m2, b2r + s);
        m2 = fmaf(spk2f, nthr2, m2);
        bool sp2 = m2 > thr2r;
        spk2f = sp2 ? 1.0f : 0.0f;
        unsigned long long mask = __ballot(sp2);
        if (lane == 0) *spkp = (unsigned short)(mask & 0xFFFFu);
        spkp += BATCH * 32;
    };
    auto g2sc = [&](float* cb) __attribute__((always_inline)) {
        union { uint4 u; short8 s; } af;
        af.u = *(uint4*)(awp + rdo);
        f32x4 C2 = { 0.f, 0.f, 0.f, 0.f };
        C2 = __builtin_amdgcn_mfma_f32_16x16x32_bf16(af.s, bhi, C2, 0, 0, 0);
        C2 = __builtin_amdgcn_mfma_f32_16x16x32_bf16(af.s, blo, C2, 0, 0, 0);
        cb[sidx]        = C2[0];
        cb[sidx + 1024] = C2[1];
        cb[sidx + 2048] = C2[2];
        cb[sidx + 3072] = C2[3];
    };

    f32x4 D0[2], D1[2];
    gemm1(xP, D0);          // GEMM1(0)

#pragma unroll 1
    for (int i = 0; i < T_STEPS; i += 2) {
        // ---- instance A: step i. reduce(i-1) from buf1; scatter(i) -> buf0
        {
            const float* rb = Cbuf[1];
            float s0 = rb[ridx], s1 = rb[ridx + 64], s2 = rb[ridx + 128], s3 = rb[ridx + 192];
            lifpack(D0);                         // spikes(i) from D0
#pragma unroll
            for (int f = 0; f < 3; ++f) xP[f] = *(const uint4*)(xpA + f * 512);
            xpA += 24576;                        // prefetch x(i+2)
            gemm1(xQ, D1);                       // GEMM1(i+1)
            if (i) rtail(s0, s1, s2, s3);        // LIF2(i-1)
            g2sc(Cbuf[0]);                       // GEMM2(i) + scatter
        }
        LDS_BARRIER();
        // ---- instance B: step i+1. reduce(i) from buf0; scatter(i+1) -> buf1
        {
            const float* rb = Cbuf[0];
            float s0 = rb[ridx], s1 = rb[ridx + 64], s2 = rb[ridx + 128], s3 = rb[ridx + 192];
            lifpack(D1);                         // spikes(i+1) from D1
#pragma unroll
            for (int f = 0; f < 3; ++f) xQ[f] = *(const uint4*)(xpB + f * 512);
            xpB += 24576;                        // prefetch x(i+3)
            gemm1(xP, D0);                       // GEMM1(i+2) (last iter: unused)
            rtail(s0, s1, s2, s3);               // LIF2(i)
            g2sc(Cbuf[1]);                       // GEMM2(i+1) + scatter
        }
        LDS_BARRIER();
    }
    // epilogue: reduce + LIF2 for step 255 (in buf1)
    {
        const float* rb = Cbuf[1];
        float s0 = rb[ridx], s1 = rb[ridx + 64], s2 = rb[ridx + 128], s3 = rb[ridx + 192];
        rtail(s0, s1, s2, s3);
    }
}

// ---- action bit-GEMM + beta-weighted scan over t (R3..R7-proven) ----
__global__ __launch_bounds__(256) void k_act(
    const unsigned short* __restrict__ spkbits,
    const float* __restrict__ Wa, const float* __restrict__ ba,
    const float* __restrict__ beta_act_p, float* __restrict__ out)
{
    __shared__ f32x4 waT[512];
    __shared__ f32x4 sc[256];
    int tid = threadIdx.x;   // = timestep
    int b   = blockIdx.x;

    for (int j = tid; j < 512; j += 256) {
        f32x4 v = { Wa[j], Wa[512 + j], Wa[1024 + j], Wa[1536 + j] };
        waT[j] = v;
    }
    float bact = fminf(fmaxf(beta_act_p[0], 0.0f), 1.0f);
    f32x4 acc = { ba[0], ba[1], ba[2], ba[3] };
    __syncthreads();

    const unsigned short* sp = spkbits + ((size_t)tid * BATCH + b) * 32;
    unsigned int wbuf[16];
#pragma unroll
    for (int r = 0; r < 4; ++r) {
        uint4 v = *(const uint4*)(sp + r * 8);
        wbuf[r*4+0] = v.x; wbuf[r*4+1] = v.y; wbuf[r*4+2] = v.z; wbuf[r*4+3] = v.w;
    }
    for (int s = 0; s < 32; ++s) {
        unsigned int wd = (wbuf[s >> 1] >> ((s & 1) * 16)) & 0xFFFFu;
#pragma unroll
        for (int i = 0; i < 16; ++i) {
            float sel = ((wd >> i) & 1u) ? 1.0f : 0.0f;
            f32x4 wv = waT[s * 16 + i];
            acc[0] = fmaf(sel, wv[0], acc[0]);
            acc[1] = fmaf(sel, wv[1], acc[1]);
            acc[2] = fmaf(sel, wv[2], acc[2]);
            acc[3] = fmaf(sel, wv[3], acc[3]);
        }
    }
    sc[tid] = acc;
    __syncthreads();
    float bd = bact;
    for (int d = 1; d < 256; d <<= 1) {
        f32x4 cv = sc[tid];
        f32x4 pv = { 0.f, 0.f, 0.f, 0.f };
        if (tid >= d) pv = sc[tid - d];
        __syncthreads();
        cv[0] = fmaf(bd, pv[0], cv[0]);
        cv[1] = fmaf(bd, pv[1], cv[1]);
        cv[2] = fmaf(bd, pv[2], cv[2]);
        cv[3] = fmaf(bd, pv[3], cv[3]);
        sc[tid] = cv;
        __syncthreads();
        bd *= bd;
    }
    f32x4 res = sc[tid];
    *(f32x4*)(out + (size_t)tid * 512 + b * 4) = res;
}

extern "C" void kernel_launch(void* const* d_in, const int* in_sizes, int n_in,
                              void* d_out, int out_size, void* d_ws, size_t ws_size,
                              hipStream_t stream)
{
    const float* batch    = (const float*)d_in[0];
    const float* W1       = (const float*)d_in[1];
    const float* b1       = (const float*)d_in[2];
    const float* beta1    = (const float*)d_in[3];
    const float* thr1     = (const float*)d_in[4];
    const float* W2       = (const float*)d_in[5];
    const float* b2       = (const float*)d_in[6];
    const float* beta2    = (const float*)d_in[7];
    const float* thr2     = (const float*)d_in[8];
    const float* Wa       = (const float*)d_in[9];
    const float* ba       = (const float*)d_in[10];
    const float* beta_act = (const float*)d_in[11];
    const float* inp_min  = (const float*)d_in[12];
    const float* inp_max  = (const float*)d_in[13];
    float* out            = (float*)d_out;

    char* ws = (char*)d_ws;
    unsigned short* W2hi    = (unsigned short*)ws;                          // 512 KiB
    unsigned short* W2lo    = (unsigned short*)(ws + (512u << 10));         // 512 KiB
    unsigned short* W1rows  = (unsigned short*)(ws + (1u << 20));           // 64 KiB
    float*          b1s     = (float*)(ws + (1u << 20) + (64u << 10));      // 2 KiB
    unsigned short* Xf      = (unsigned short*)(ws + (2u << 20));           // 6 MiB
    unsigned short* spkbits = (unsigned short*)(ws + (8u << 20));           // 2 MiB

    hipLaunchKernelGGL(k_prep, dim3(770), dim3(256), 0, stream,
                       W2, W1, b1, thr1, inp_min, inp_max, batch,
                       W2hi, W2lo, W1rows, b1s, Xf);
    hipLaunchKernelGGL(k_main, dim3(256), dim3(1024), 0, stream,
                       Xf, W2hi, W2lo, W1rows, b1s, beta1, b2, beta2, thr2, spkbits);
    hipLaunchKernelGGL(k_act, dim3(128), dim3(256), 0, stream, spkbits, Wa, ba, beta_act, out);
}